// Round 7
// baseline (181.937 us; speedup 1.0000x reference)
//
#include <hip/hip_runtime.h>

// Problem constants: NTOK=50257, NINP=512, NREL=200, N=1024, L=64, EPS=32
#define NINP 512
#define NREL 200
#define LSEQ 64
#define WT_LD 256           // padded leading dim of transposed W
#define SPB 2               // sequences per fused block

// ---------------- Kernel 1: transpose W -> Wt[k][r] (pad r in [NREL,WT_LD) with 0) ----------------
__global__ __launch_bounds__(256) void wt_kernel(
    const float* __restrict__ W,
    float* __restrict__ Wt)
{
    const int b = blockIdx.x;       // 0..255 -> k pair
    const int t = threadIdx.x;      // r
    #pragma unroll
    for (int j = 0; j < 2; ++j) {
        const int k = b * 2 + j;
        Wt[k * WT_LD + t] = (t < NREL) ? W[t * NINP + k] : 0.f;
    }
}

// ---------------- Kernel 2: fused gather + linear + loss ----------------
// grid = N/SPB = 512 blocks x 1024 threads (2 blocks/CU).
// Phase A: 8 groups x 128 threads; group g sums 16 rows (2 batches of 8
//          independent float4 loads) for sequence g/4 -> hpart -> h_lds.
// Phase B: thread (kslice=t>>8, r=t&255): 32 k4-iters of coalesced Wt loads
//          vs LDS-broadcast h float4s -> partial dots -> LDS.
// Phase C: per-relation loss terms + block reduction + global atomicAdd.
__global__ __launch_bounds__(1024) void fused_kernel(
    const int* __restrict__ seq,
    const float* __restrict__ emb,
    const float* __restrict__ Wt,    // (NINP, WT_LD)
    const int* __restrict__ rel,     // (E,)
    const float* __restrict__ bias,  // (NREL,)
    float* __restrict__ out,         // [2] (pre-zeroed)
    int N, int eps)
{
    __shared__ int    toks[SPB * LSEQ];        // 128 ids
    __shared__ float4 hpart[8][128];           // 16 KB
    __shared__ float  h_lds[SPB][NINP];        // 4 KB
    __shared__ unsigned int maskbits[SPB][8];
    __shared__ float  pd[SPB][4][256];         // 8 KB
    __shared__ float  red_logp[16];
    __shared__ float  red_acc[16];

    const int i0 = blockIdx.x * SPB;
    const int t  = threadIdx.x;

    if (t < SPB * LSEQ) toks[t] = seq[i0 * LSEQ + t];
    if (t >= 512 && t < 512 + SPB * 8) ((unsigned int*)maskbits)[t - 512] = 0u;
    __syncthreads();

    // ---- Phase A: gather ----
    const int g = t >> 7;        // 0..7 (wave-uniform)
    const int e = t & 127;       // float4 index within row
    float4 acc = make_float4(0.f, 0.f, 0.f, 0.f);
    #pragma unroll
    for (int batch = 0; batch < 2; ++batch) {
        const int base = g * 16 + batch * 8;
        float4 v[8];
        #pragma unroll
        for (int j = 0; j < 8; ++j) {
            const int tok = __builtin_amdgcn_readfirstlane(toks[base + j]);
            v[j] = ((const float4*)(emb + (long)tok * NINP))[e];
        }
        float4 s01, s23, s45, s67;
        s01.x = v[0].x + v[1].x; s01.y = v[0].y + v[1].y; s01.z = v[0].z + v[1].z; s01.w = v[0].w + v[1].w;
        s23.x = v[2].x + v[3].x; s23.y = v[2].y + v[3].y; s23.z = v[2].z + v[3].z; s23.w = v[2].w + v[3].w;
        s45.x = v[4].x + v[5].x; s45.y = v[4].y + v[5].y; s45.z = v[4].z + v[5].z; s45.w = v[4].w + v[5].w;
        s67.x = v[6].x + v[7].x; s67.y = v[6].y + v[7].y; s67.z = v[6].z + v[7].z; s67.w = v[6].w + v[7].w;
        acc.x += (s01.x + s23.x) + (s45.x + s67.x);
        acc.y += (s01.y + s23.y) + (s45.y + s67.y);
        acc.z += (s01.z + s23.z) + (s45.z + s67.z);
        acc.w += (s01.w + s23.w) + (s45.w + s67.w);
    }
    hpart[g][e] = acc;
    __syncthreads();

    // combine 4 groups per sequence -> h_lds; also build relation bitmask
    if (t < SPB * 128) {
        const int s = t >> 7, ee = t & 127;
        float4 a0 = hpart[4 * s + 0][ee];
        float4 a1 = hpart[4 * s + 1][ee];
        float4 a2 = hpart[4 * s + 2][ee];
        float4 a3 = hpart[4 * s + 3][ee];
        float4 c;
        c.x = (a0.x + a1.x) + (a2.x + a3.x);
        c.y = (a0.y + a1.y) + (a2.y + a3.y);
        c.z = (a0.z + a1.z) + (a2.z + a3.z);
        c.w = (a0.w + a1.w) + (a2.w + a3.w);
        ((float4*)h_lds)[t] = c;
    }
    if (t >= 512 && t < 512 + SPB * 32) {
        const int s = (t - 512) >> 5, j = (t - 512) & 31;
        if (j < eps) {
            int r = rel[(i0 + s) * eps + j];
            atomicOr(&maskbits[s][r >> 5], 1u << (r & 31));
        }
    }
    __syncthreads();

    // ---- Phase B: logits ----
    const int kslice = t >> 8;   // 0..3
    const int r      = t & 255;
    float d0 = 0.f, d1 = 0.f;
    const float4* h40 = (const float4*)h_lds[0];
    const float4* h41 = (const float4*)h_lds[1];
    #pragma unroll 4
    for (int k4 = kslice * 32; k4 < kslice * 32 + 32; ++k4) {
        const int k = k4 * 4;
        const float w0 = Wt[(k + 0) * WT_LD + r];  // coalesced
        const float w1 = Wt[(k + 1) * WT_LD + r];
        const float w2 = Wt[(k + 2) * WT_LD + r];
        const float w3 = Wt[(k + 3) * WT_LD + r];
        const float4 hv0 = h40[k4];                // LDS broadcast
        const float4 hv1 = h41[k4];
        d0 += w0 * hv0.x + w1 * hv0.y + w2 * hv0.z + w3 * hv0.w;
        d1 += w0 * hv1.x + w1 * hv1.y + w2 * hv1.z + w3 * hv1.w;
    }
    pd[0][kslice][r] = d0;
    pd[1][kslice][r] = d1;
    __syncthreads();

    // ---- Phase C: loss terms + reduction ----
    float term = 0.f, match = 0.f;
    if (t < NREL) {
        const float bt = bias[t];
        #pragma unroll
        for (int s = 0; s < SPB; ++s) {
            const float dot = ((pd[s][0][t] + pd[s][1][t]) +
                               (pd[s][2][t] + pd[s][3][t])) + bt;
            const unsigned mb = (maskbits[s][t >> 5] >> (t & 31)) & 1u;
            float tr;
            if (mb) {
                tr = fminf(dot, 0.f) - log1pf(expf(-fabsf(dot)));  // log_sigmoid
            } else {
                tr = logf(1e-5f + 1.f / (1.f + expf(dot)));        // log(1e-5+sig(-x))
            }
            term  += tr;
            match += (((dot > 0.5f) ? 1u : 0u) == mb) ? 1.f : 0.f;
        }
    }

    #pragma unroll
    for (int off = 32; off > 0; off >>= 1) {
        term  += __shfl_down(term,  off);
        match += __shfl_down(match, off);
    }
    const int wave = t >> 6;
    const int lane = t & 63;
    if (lane == 0) { red_logp[wave] = term; red_acc[wave] = match; }
    __syncthreads();
    if (t == 0) {
        float s = 0.f, a = 0.f;
        #pragma unroll
        for (int w = 0; w < 16; ++w) { s += red_logp[w]; a += red_acc[w]; }
        atomicAdd(out + 0, s / (float)N);
        atomicAdd(out + 1, a / ((float)N * (float)NREL));
    }
}

extern "C" void kernel_launch(void* const* d_in, const int* in_sizes, int n_in,
                              void* d_out, int out_size, void* d_ws, size_t ws_size,
                              hipStream_t stream) {
    const int*   seq = (const int*)d_in[0];
    const int*   m   = (const int*)d_in[1]; (void)m;
    const int*   rel = (const int*)d_in[2];
    const float* emb = (const float*)d_in[3];
    const float* W   = (const float*)d_in[4];
    const float* b   = (const float*)d_in[5];
    float* out = (float*)d_out;

    const int N   = in_sizes[1];               // 1024
    const int eps = in_sizes[2] / N;           // 32

    float* Wt = (float*)d_ws;                  // 512 KB

    hipMemsetAsync(out, 0, 2 * sizeof(float), stream);
    wt_kernel<<<NINP / 2, 256, 0, stream>>>(W, Wt);
    fused_kernel<<<N / SPB, 1024, 0, stream>>>(seq, emb, Wt, rel, b, out, N, eps);
}

// Round 8
// 169.647 us; speedup vs baseline: 1.0724x; 1.0724x over previous
//
#include <hip/hip_runtime.h>

// Problem constants: NTOK=50257, NINP=512, NREL=200, N=1024, L=64, EPS=32
#define NINP 512
#define NREL 200
#define LSEQ 64
#define WT_LD 256           // padded leading dim of transposed W
#define SPB 4               // sequences per fused block

// ---------------- Kernel 1: transpose W -> Wt[k][r] (pad r in [NREL,WT_LD) with 0) ----------------
__global__ __launch_bounds__(256) void wt_kernel(
    const float* __restrict__ W,
    float* __restrict__ Wt)
{
    const int b = blockIdx.x;       // 0..255 -> k pair
    const int t = threadIdx.x;      // r
    #pragma unroll
    for (int j = 0; j < 2; ++j) {
        const int k = b * 2 + j;
        Wt[k * WT_LD + t] = (t < NREL) ? W[t * NINP + k] : 0.f;
    }
}

// ---------------- Kernel 2: fused gather + linear + loss ----------------
// grid = N/SPB = 256 blocks x 1024 threads (1 block/CU, 16 waves).
// Phase A: wave w (= seq s=w>>2, quarter q=w&3) sums 16 rows; lane holds
//          float4 slots {lane, 64+lane}; 4-row batches of 8 indep loads.
// Pack:    h_pack[k][s] so one ds_read_b128 broadcasts h[k] for 4 seqs.
// Phase B: wave = kslice (32 k each); lane covers 4 relations (float4 Wt).
//          Per k: 1 broadcast ds_read + 1 Wt float4 + 16 FMA. Partials to
//          pd[wave][s][lane] (float4), no atomics.
// Phase C: thread (s=t>>8, r=t&255) sums 16 wave-partials (conflict-free),
//          + bias, loss terms, block reduction, 2 global atomicAdds.
__global__ __launch_bounds__(1024) void fused_kernel(
    const int* __restrict__ seq,
    const float* __restrict__ emb,
    const float* __restrict__ Wt,    // (NINP, WT_LD)
    const int* __restrict__ rel,     // (E,)
    const float* __restrict__ bias,  // (NREL,)
    float* __restrict__ out,         // [2] (pre-zeroed)
    int N, int eps)
{
    __shared__ int    toks[SPB * LSEQ];        // 1 KB
    __shared__ float4 hpart[16][2][64];        // 32 KB  [wave][half][lane]
    __shared__ float  h_pack[NINP][SPB];       // 8 KB   [k][s]
    __shared__ float4 pd[16][SPB][64];         // 64 KB  [wave][s][lane]
    __shared__ unsigned int maskbits[SPB][8];
    __shared__ float  red_lp[16], red_ac[16];

    const int i0   = blockIdx.x * SPB;
    const int t    = threadIdx.x;
    const int wave = t >> 6;
    const int lane = t & 63;

    if (t < SPB * LSEQ) toks[t] = seq[i0 * LSEQ + t];
    if (t < SPB * 8) ((unsigned int*)maskbits)[t] = 0u;
    __syncthreads();

    if (t < SPB * 32) {
        const int s = t >> 5, j = t & 31;
        if (j < eps) {
            int r = rel[(i0 + s) * eps + j];
            atomicOr(&maskbits[s][r >> 5], 1u << (r & 31));
        }
    }

    // ---- Phase A: gather 16 rows per wave ----
    {
        const int rbase = (wave >> 2) * LSEQ + (wave & 3) * 16;
        float4 lo = make_float4(0.f, 0.f, 0.f, 0.f);
        float4 hi = lo;
        #pragma unroll
        for (int j0 = 0; j0 < 16; j0 += 4) {
            const float* r0 = emb + (long)__builtin_amdgcn_readfirstlane(toks[rbase + j0 + 0]) * NINP;
            const float* r1 = emb + (long)__builtin_amdgcn_readfirstlane(toks[rbase + j0 + 1]) * NINP;
            const float* r2 = emb + (long)__builtin_amdgcn_readfirstlane(toks[rbase + j0 + 2]) * NINP;
            const float* r3 = emb + (long)__builtin_amdgcn_readfirstlane(toks[rbase + j0 + 3]) * NINP;
            float4 l0 = ((const float4*)r0)[lane];
            float4 h0 = ((const float4*)r0)[64 + lane];
            float4 l1 = ((const float4*)r1)[lane];
            float4 h1 = ((const float4*)r1)[64 + lane];
            float4 l2 = ((const float4*)r2)[lane];
            float4 h2 = ((const float4*)r2)[64 + lane];
            float4 l3 = ((const float4*)r3)[lane];
            float4 h3 = ((const float4*)r3)[64 + lane];
            lo.x += (l0.x + l1.x) + (l2.x + l3.x);
            lo.y += (l0.y + l1.y) + (l2.y + l3.y);
            lo.z += (l0.z + l1.z) + (l2.z + l3.z);
            lo.w += (l0.w + l1.w) + (l2.w + l3.w);
            hi.x += (h0.x + h1.x) + (h2.x + h3.x);
            hi.y += (h0.y + h1.y) + (h2.y + h3.y);
            hi.z += (h0.z + h1.z) + (h2.z + h3.z);
            hi.w += (h0.w + h1.w) + (h2.w + h3.w);
        }
        hpart[wave][0][lane] = lo;
        hpart[wave][1][lane] = hi;
    }
    __syncthreads();

    // ---- Pack: h_pack[k][s] = sum of 4 quarter-partials ----
    {
        float2 v;
        #pragma unroll
        for (int d = 0; d < 2; ++d) {
            const int idx = 2 * t + d;          // = k*4 + s
            const int s = idx & 3;
            const int k = idx >> 2;
            const int f = k >> 2, c = k & 3;
            const int half = f >> 6, lf = f & 63;
            float sum = 0.f;
            #pragma unroll
            for (int q = 0; q < 4; ++q)
                sum += ((const float*)&hpart[s * 4 + q][half][lf])[c];
            ((float*)&v)[d] = sum;
        }
        ((float2*)h_pack)[t] = v;
    }
    __syncthreads();

    // ---- Phase B: partial dots ----
    {
        const float4* Wt4 = (const float4*)Wt;     // [k][64]
        float4 a0 = make_float4(0.f, 0.f, 0.f, 0.f);
        float4 a1 = a0, a2 = a0, a3 = a0;          // acc[s] over 4 relations
        const int kbase = wave * 32;
        #pragma unroll 4
        for (int k = kbase; k < kbase + 32; ++k) {
            const float4 wv = Wt4[k * 64 + lane];            // coalesced 1KB
            const float4 hp = ((const float4*)h_pack)[k];    // broadcast: h[k] for s=0..3
            a0.x += hp.x * wv.x; a0.y += hp.x * wv.y; a0.z += hp.x * wv.z; a0.w += hp.x * wv.w;
            a1.x += hp.y * wv.x; a1.y += hp.y * wv.y; a1.z += hp.y * wv.z; a1.w += hp.y * wv.w;
            a2.x += hp.z * wv.x; a2.y += hp.z * wv.y; a2.z += hp.z * wv.z; a2.w += hp.z * wv.w;
            a3.x += hp.w * wv.x; a3.y += hp.w * wv.y; a3.z += hp.w * wv.z; a3.w += hp.w * wv.w;
        }
        pd[wave][0][lane] = a0;
        pd[wave][1][lane] = a1;
        pd[wave][2][lane] = a2;
        pd[wave][3][lane] = a3;
    }
    __syncthreads();

    // ---- Phase C: reduce partials, loss terms, block reduction ----
    float term = 0.f, match = 0.f;
    {
        const int s = t >> 8;        // 0..3
        const int r = t & 255;       // 0..255
        if (r < NREL) {
            const int f = r >> 2, c = r & 3;
            float dot = bias[r];
            #pragma unroll
            for (int w = 0; w < 16; ++w)
                dot += ((const float*)&pd[w][s][f])[c];   // lanes consecutive r -> conflict-free
            const unsigned mb = (maskbits[s][r >> 5] >> (r & 31)) & 1u;
            if (mb) {
                term = fminf(dot, 0.f) - log1pf(expf(-fabsf(dot)));  // log_sigmoid
            } else {
                term = logf(1e-5f + 1.f / (1.f + expf(dot)));        // log(1e-5+sig(-x))
            }
            match = (((dot > 0.5f) ? 1u : 0u) == mb) ? 1.f : 0.f;
        }
    }

    #pragma unroll
    for (int off = 32; off > 0; off >>= 1) {
        term  += __shfl_down(term,  off);
        match += __shfl_down(match, off);
    }
    if (lane == 0) { red_lp[wave] = term; red_ac[wave] = match; }
    __syncthreads();
    if (t == 0) {
        float s = 0.f, a = 0.f;
        #pragma unroll
        for (int w = 0; w < 16; ++w) { s += red_lp[w]; a += red_ac[w]; }
        atomicAdd(out + 0, s / (float)N);
        atomicAdd(out + 1, a / ((float)N * (float)NREL));
    }
}

extern "C" void kernel_launch(void* const* d_in, const int* in_sizes, int n_in,
                              void* d_out, int out_size, void* d_ws, size_t ws_size,
                              hipStream_t stream) {
    const int*   seq = (const int*)d_in[0];
    const int*   m   = (const int*)d_in[1]; (void)m;
    const int*   rel = (const int*)d_in[2];
    const float* emb = (const float*)d_in[3];
    const float* W   = (const float*)d_in[4];
    const float* b   = (const float*)d_in[5];
    float* out = (float*)d_out;

    const int N   = in_sizes[1];               // 1024
    const int eps = in_sizes[2] / N;           // 32

    float* Wt = (float*)d_ws;                  // 512 KB

    hipMemsetAsync(out, 0, 2 * sizeof(float), stream);
    wt_kernel<<<NINP / 2, 256, 0, stream>>>(W, Wt);
    fused_kernel<<<N / SPB, 1024, 0, stream>>>(seq, emb, Wt, rel, b, out, N, eps);
}

// Round 10
// 169.159 us; speedup vs baseline: 1.0755x; 1.0029x over previous
//
#include <hip/hip_runtime.h>

// Problem constants: NTOK=50257, NINP=512, NREL=200, N=1024, L=64, EPS=32
#define NINP 512
#define NREL 200
#define LSEQ 64
#define WT_LD 256           // padded leading dim of transposed W
#define SPB 4               // sequences per fused block

typedef float vfloat4 __attribute__((ext_vector_type(4)));  // native vec for nt builtins

// ---------------- Kernel 1: transpose W -> Wt[k][r] (pad r in [NREL,WT_LD) with 0) ----------------
__global__ __launch_bounds__(256) void wt_kernel(
    const float* __restrict__ W,
    float* __restrict__ Wt)
{
    const int b = blockIdx.x;       // 0..255 -> k pair
    const int t = threadIdx.x;      // r
    #pragma unroll
    for (int j = 0; j < 2; ++j) {
        const int k = b * 2 + j;
        Wt[k * WT_LD + t] = (t < NREL) ? W[t * NINP + k] : 0.f;
    }
}

// ---------------- Kernel 2: fused gather + linear + loss ----------------
// grid = N/SPB = 256 blocks x 1024 threads (1 block/CU, 16 waves).
// Phase A: wave w (= seq s=w>>2, quarter q=w&3) sums 16 rows in 2 batches of
//          8 rows; 16 independent NON-TEMPORAL float4 loads per batch (no L1
//          allocation — gathered rows have zero L1 reuse).
// Pack:    h_pack[k][s] so one ds_read_b128 broadcasts h[k] for 4 seqs.
// Phase B: wave = kslice (32 k each); lane covers 4 relations (float4 Wt).
//          Per k: 1 broadcast ds_read + 1 Wt float4 + 16 FMA.
// Phase C: thread (s=t>>8, r=t&255) sums 16 wave-partials, + bias, loss
//          terms, block reduction, 2 global atomicAdds.
__global__ __launch_bounds__(1024) void fused_kernel(
    const int* __restrict__ seq,
    const float* __restrict__ emb,
    const float* __restrict__ Wt,    // (NINP, WT_LD)
    const int* __restrict__ rel,     // (E,)
    const float* __restrict__ bias,  // (NREL,)
    float* __restrict__ out,         // [2] (pre-zeroed)
    int N, int eps)
{
    __shared__ int    toks[SPB * LSEQ];        // 1 KB
    __shared__ vfloat4 hpart[16][2][64];       // 32 KB  [wave][half][lane]
    __shared__ float  h_pack[NINP][SPB];       // 8 KB   [k][s]
    __shared__ float4 pd[16][SPB][64];         // 64 KB  [wave][s][lane]
    __shared__ unsigned int maskbits[SPB][8];
    __shared__ float  red_lp[16], red_ac[16];

    const int i0   = blockIdx.x * SPB;
    const int t    = threadIdx.x;
    const int wave = t >> 6;
    const int lane = t & 63;

    if (t < SPB * LSEQ) toks[t] = seq[i0 * LSEQ + t];
    if (t < SPB * 8) ((unsigned int*)maskbits)[t] = 0u;
    __syncthreads();

    if (t < SPB * 32) {
        const int s = t >> 5, j = t & 31;
        if (j < eps) {
            int r = rel[(i0 + s) * eps + j];
            atomicOr(&maskbits[s][r >> 5], 1u << (r & 31));
        }
    }

    // ---- Phase A: gather 16 rows per wave, 8-row batches, nt loads ----
    {
        const int rbase = (wave >> 2) * LSEQ + (wave & 3) * 16;
        vfloat4 lo = (vfloat4)0.f;
        vfloat4 hi = (vfloat4)0.f;
        #pragma unroll
        for (int j0 = 0; j0 < 16; j0 += 8) {
            const vfloat4* rp[8];
            #pragma unroll
            for (int j = 0; j < 8; ++j)
                rp[j] = (const vfloat4*)(emb +
                    (long)__builtin_amdgcn_readfirstlane(toks[rbase + j0 + j]) * NINP);
            vfloat4 l[8], h[8];
            #pragma unroll
            for (int j = 0; j < 8; ++j) {
                l[j] = __builtin_nontemporal_load(rp[j] + lane);
                h[j] = __builtin_nontemporal_load(rp[j] + 64 + lane);
            }
            #pragma unroll
            for (int j = 0; j < 4; ++j) {        // pairwise tree, retire early
                l[j] = l[2*j] + l[2*j+1];
                h[j] = h[2*j] + h[2*j+1];
            }
            lo += (l[0] + l[1]) + (l[2] + l[3]);
            hi += (h[0] + h[1]) + (h[2] + h[3]);
        }
        hpart[wave][0][lane] = lo;
        hpart[wave][1][lane] = hi;
    }
    __syncthreads();

    // ---- Pack: h_pack[k][s] = sum of 4 quarter-partials ----
    {
        float2 v;
        #pragma unroll
        for (int d = 0; d < 2; ++d) {
            const int idx = 2 * t + d;          // = k*4 + s
            const int s = idx & 3;
            const int k = idx >> 2;
            const int f = k >> 2, c = k & 3;
            const int half = f >> 6, lf = f & 63;
            float sum = 0.f;
            #pragma unroll
            for (int q = 0; q < 4; ++q)
                sum += ((const float*)&hpart[s * 4 + q][half][lf])[c];
            ((float*)&v)[d] = sum;
        }
        ((float2*)h_pack)[t] = v;
    }
    __syncthreads();

    // ---- Phase B: partial dots ----
    {
        const float4* Wt4 = (const float4*)Wt;     // [k][64]
        float4 a0 = make_float4(0.f, 0.f, 0.f, 0.f);
        float4 a1 = a0, a2 = a0, a3 = a0;          // acc[s] over 4 relations
        const int kbase = wave * 32;
        #pragma unroll 4
        for (int k = kbase; k < kbase + 32; ++k) {
            const float4 wv = Wt4[k * 64 + lane];            // coalesced 1KB
            const float4 hp = ((const float4*)h_pack)[k];    // broadcast: h[k] for s=0..3
            a0.x += hp.x * wv.x; a0.y += hp.x * wv.y; a0.z += hp.x * wv.z; a0.w += hp.x * wv.w;
            a1.x += hp.y * wv.x; a1.y += hp.y * wv.y; a1.z += hp.y * wv.z; a1.w += hp.y * wv.w;
            a2.x += hp.z * wv.x; a2.y += hp.z * wv.y; a2.z += hp.z * wv.z; a2.w += hp.z * wv.w;
            a3.x += hp.w * wv.x; a3.y += hp.w * wv.y; a3.z += hp.w * wv.z; a3.w += hp.w * wv.w;
        }
        pd[wave][0][lane] = a0;
        pd[wave][1][lane] = a1;
        pd[wave][2][lane] = a2;
        pd[wave][3][lane] = a3;
    }
    __syncthreads();

    // ---- Phase C: reduce partials, loss terms, block reduction ----
    float term = 0.f, match = 0.f;
    {
        const int s = t >> 8;        // 0..3
        const int r = t & 255;       // 0..255
        if (r < NREL) {
            const int f = r >> 2, c = r & 3;
            float dot = bias[r];
            #pragma unroll
            for (int w = 0; w < 16; ++w)
                dot += ((const float*)&pd[w][s][f])[c];   // consecutive r -> conflict-free
            const unsigned mb = (maskbits[s][r >> 5] >> (r & 31)) & 1u;
            if (mb) {
                term = fminf(dot, 0.f) - log1pf(expf(-fabsf(dot)));  // log_sigmoid
            } else {
                term = logf(1e-5f + 1.f / (1.f + expf(dot)));        // log(1e-5+sig(-x))
            }
            match = (((dot > 0.5f) ? 1u : 0u) == mb) ? 1.f : 0.f;
        }
    }

    #pragma unroll
    for (int off = 32; off > 0; off >>= 1) {
        term  += __shfl_down(term,  off);
        match += __shfl_down(match, off);
    }
    if (lane == 0) { red_lp[wave] = term; red_ac[wave] = match; }
    __syncthreads();
    if (t == 0) {
        float s = 0.f, a = 0.f;
        #pragma unroll
        for (int w = 0; w < 16; ++w) { s += red_lp[w]; a += red_ac[w]; }
        atomicAdd(out + 0, s / (float)N);
        atomicAdd(out + 1, a / ((float)N * (float)NREL));
    }
}

extern "C" void kernel_launch(void* const* d_in, const int* in_sizes, int n_in,
                              void* d_out, int out_size, void* d_ws, size_t ws_size,
                              hipStream_t stream) {
    const int*   seq = (const int*)d_in[0];
    const int*   m   = (const int*)d_in[1]; (void)m;
    const int*   rel = (const int*)d_in[2];
    const float* emb = (const float*)d_in[3];
    const float* W   = (const float*)d_in[4];
    const float* b   = (const float*)d_in[5];
    float* out = (float*)d_out;

    const int N   = in_sizes[1];               // 1024
    const int eps = in_sizes[2] / N;           // 32

    float* Wt = (float*)d_ws;                  // 512 KB

    hipMemsetAsync(out, 0, 2 * sizeof(float), stream);
    wt_kernel<<<NINP / 2, 256, 0, stream>>>(W, Wt);
    fused_kernel<<<N / SPB, 1024, 0, stream>>>(seq, emb, Wt, rel, b, out, N, eps);
}